// Round 1
// baseline (93.703 us; speedup 1.0000x reference)
//
#include <hip/hip_runtime.h>

// FlowNet correlation: out[b, pp*9+oo, y, x] =
//   mean_c first[b,c,y,x] * second[b,c, y+pp-4, x+oo-4]   (zero outside)
//
// B=4 C=128 H=128 W=256, 81 displacements.
// Block = (b, y-pair). Thread = (ysub, 8-pixel x-group, p-row). 72 fp32 acc.
// Per-channel LDS staging, double-buffered, async-split prefetch (T14).

namespace {
constexpr int kPad = 4;
constexpr int kWin = 9;                       // 2*kPad+1
constexpr int kB = 4, kC = 128, kH = 128, kW = 256;
constexpr int kTY = 2;                        // y-rows per block
constexpr int kPX = 8;                        // x-pixels per thread
constexpr int kXG = kW / kPX;                 // 32 x-groups
constexpr int kThreads = kTY * kXG * kWin;    // 576
constexpr int kSRows = kTY + 2 * kPad;        // 10 second-rows (with halo)
constexpr int kSStr = 292;                    // s-row LDS stride (floats); 292 mod 32 = 4 banks
constexpr int kFOff = kSRows * kSStr;         // 2920: first-rows offset in buffer
constexpr int kBufSz = kFOff + kTY * kW;      // 3432 floats per buffer
constexpr int kS4 = (kW + 2 * kPad) / 4;      // 66 float4 per s-row
constexpr int kNS4 = kSRows * kS4;            // 660
constexpr int kNF4 = kTY * (kW / 4);          // 128
constexpr int kTot4 = kNS4 + kNF4;            // 788 float4 staged per channel
constexpr int kBlocks = kB * kH / kTY;        // 256
}  // namespace

__global__ __launch_bounds__(kThreads) void corr_kernel(
    const float* __restrict__ first,
    const float* __restrict__ second,
    float* __restrict__ out)
{
    __shared__ float lds[2 * kBufSz];

    const int tid  = threadIdx.x;
    const int p    = tid % kWin;                 // displacement row 0..8
    const int xg   = (tid / kWin) % kXG;         // x-group
    const int ysub = tid / (kWin * kXG);         // 0..1
    const int x0   = xg * kPX;

    // XCD-aware bijective swizzle: 256 blocks = 8 XCDs x 32 contiguous works,
    // so y-adjacent blocks (sharing second-row halo) land on the same XCD L2.
    int bid = blockIdx.x;
    bid = (bid & 7) * (kBlocks / 8) + (bid >> 3);
    const int b  = bid / (kH / kTY);
    const int y0 = (bid % (kH / kTY)) * kTY;

    const size_t cstr = (size_t)kH * kW;

    // --- staging roles: each thread stages up to 2 float4 per channel ---
    const float* g0 = nullptr; int l0 = -1;
    const float* g1 = nullptr; int l1 = -1;
    {
        // role 0: idx = tid (< 660, always a second-row element)
        int r = tid / kS4, j = tid - r * kS4;
        int y = y0 - kPad + r;
        l0 = r * kSStr + 4 * j;
        if (y >= 0 && y < kH && j >= 1 && j <= kW / 4)
            g0 = second + ((size_t)(b * kC) * kH + (size_t)y) * kW + (4 * j - 4);
    }
    {
        int idx = tid + kThreads;
        if (idx < kNS4) {
            int r = idx / kS4, j = idx - r * kS4;
            int y = y0 - kPad + r;
            l1 = r * kSStr + 4 * j;
            if (y >= 0 && y < kH && j >= 1 && j <= kW / 4)
                g1 = second + ((size_t)(b * kC) * kH + (size_t)y) * kW + (4 * j - 4);
        } else if (idx < kTot4) {
            int i = idx - kNS4;
            int ys = i >> 6, j = i & 63;
            l1 = kFOff + ys * kW + 4 * j;
            g1 = first + ((size_t)(b * kC) * kH + (size_t)(y0 + ys)) * kW + 4 * j;
        }
    }

    float acc[kWin * kPX];
#pragma unroll
    for (int i = 0; i < kWin * kPX; ++i) acc[i] = 0.0f;

    auto compute = [&](int cur) {
        const float* sb = &lds[cur * kBufSz + (ysub + p) * kSStr + x0];
        const float* fb = &lds[cur * kBufSz + kFOff + ysub * kW + x0];
        float w[kPX + 8], f[kPX];
        float4 t;
        t = *(const float4*)(sb + 0);  w[0]=t.x;  w[1]=t.y;  w[2]=t.z;  w[3]=t.w;
        t = *(const float4*)(sb + 4);  w[4]=t.x;  w[5]=t.y;  w[6]=t.z;  w[7]=t.w;
        t = *(const float4*)(sb + 8);  w[8]=t.x;  w[9]=t.y;  w[10]=t.z; w[11]=t.w;
        t = *(const float4*)(sb + 12); w[12]=t.x; w[13]=t.y; w[14]=t.z; w[15]=t.w;
        t = *(const float4*)(fb + 0);  f[0]=t.x;  f[1]=t.y;  f[2]=t.z;  f[3]=t.w;
        t = *(const float4*)(fb + 4);  f[4]=t.x;  f[5]=t.y;  f[6]=t.z;  f[7]=t.w;
#pragma unroll
        for (int o = 0; o < kWin; ++o)
#pragma unroll
            for (int j = 0; j < kPX; ++j)
                acc[o * kPX + j] = fmaf(f[j], w[j + o], acc[o * kPX + j]);
    };

    // --- prologue: stage channel 0 ---
    float4 pf0 = make_float4(0.f, 0.f, 0.f, 0.f);
    float4 pf1 = make_float4(0.f, 0.f, 0.f, 0.f);
    if (g0) { pf0 = *(const float4*)g0; g0 += cstr; }
    if (g1) { pf1 = *(const float4*)g1; g1 += cstr; }
    if (l0 >= 0) *(float4*)&lds[l0] = pf0;
    if (l1 >= 0) *(float4*)&lds[l1] = pf1;
    __syncthreads();

    // --- main loop: prefetch c+1 (global->reg), compute c, write c+1, barrier ---
    int cur = 0;
    for (int c = 0; c < kC - 1; ++c) {
        if (g0) { pf0 = *(const float4*)g0; g0 += cstr; }
        if (g1) { pf1 = *(const float4*)g1; g1 += cstr; }
        compute(cur);
        const int nb = (cur ^ 1) * kBufSz;
        if (l0 >= 0) *(float4*)&lds[nb + l0] = pf0;
        if (l1 >= 0) *(float4*)&lds[nb + l1] = pf1;
        __syncthreads();
        cur ^= 1;
    }
    compute(cur);

    // --- epilogue: mean (x 1/128) and store, 2x float4 per displacement ---
    const float inv = 1.0f / (float)kC;
    const size_t obase = (size_t)b * (kWin * kWin) * kH * kW;
#pragma unroll
    for (int o = 0; o < kWin; ++o) {
        const int d = p * kWin + o;
        float* op = out + obase + ((size_t)d * kH + (size_t)(y0 + ysub)) * kW + x0;
        float4 r0, r1;
        r0.x = acc[o * kPX + 0] * inv; r0.y = acc[o * kPX + 1] * inv;
        r0.z = acc[o * kPX + 2] * inv; r0.w = acc[o * kPX + 3] * inv;
        r1.x = acc[o * kPX + 4] * inv; r1.y = acc[o * kPX + 5] * inv;
        r1.z = acc[o * kPX + 6] * inv; r1.w = acc[o * kPX + 7] * inv;
        *(float4*)op = r0;
        *(float4*)(op + 4) = r1;
    }
}

extern "C" void kernel_launch(void* const* d_in, const int* in_sizes, int n_in,
                              void* d_out, int out_size, void* d_ws, size_t ws_size,
                              hipStream_t stream) {
    const float* first  = (const float*)d_in[0];
    const float* second = (const float*)d_in[1];
    float* out = (float*)d_out;
    dim3 grid(kBlocks);      // 256 blocks = 1 per CU
    dim3 block(kThreads);    // 576 threads = 9 waves
    hipLaunchKernelGGL(corr_kernel, grid, block, 0, stream, first, second, out);
}

// Round 2
// 86.889 us; speedup vs baseline: 1.0784x; 1.0784x over previous
//
#include <hip/hip_runtime.h>

// FlowNet correlation: out[b, pp*9+oo, y, x] =
//   mean_c first[b,c,y,x] * second[b,c, y+pp-4, x+oo-4]   (zero outside)
//
// B=4 C=128 H=128 W=256, 81 displacements.
// Round 2: block = (b, y-pair, x-half) -> 512 blocks = 2/CU (barrier overlap);
// LDS chunk swizzle c^=c>>3 kills the stride-8-bank conflicts of round 1.

namespace {
constexpr int kPad = 4;
constexpr int kWin = 9;
constexpr int kB = 4, kC = 128, kH = 128, kW = 256;
constexpr int kTY = 2;                         // y-rows per block
constexpr int kWH = 128;                       // x-half width per block
constexpr int kXG = 16;                        // x-groups of 8 per half
constexpr int kPX = 8;                         // x-pixels per thread
constexpr int kThreads = kTY * kXG * kWin;     // 288
constexpr int kSRows = kTY + 2 * kPad;         // 10 second rows (halo)
constexpr int kRowC = (kWH + 2 * kPad) / 4;    // 34 float4 chunks per s-row
constexpr int kS4 = 38;                        // row stride in chunks (post-swizzle max 37)
constexpr int kFRow = kSRows;                  // first rows stored as rows 10,11
constexpr int kBufC = (kSRows + kTY) * kS4;    // 456 chunks per buffer
constexpr int kBufF = kBufC * 4;               // 1824 floats per buffer
constexpr int kNS = kSRows * kRowC;            // 340 second chunks staged
constexpr int kNF = kTY * (kWH / 4);           // 64 first chunks staged
constexpr int kTot = kNS + kNF;                // 404
constexpr int kBlocks = kB * (kH / kTY) * 2;   // 512 -> 2 blocks/CU

__device__ __forceinline__ int swz(int c) { return c ^ (c >> 3); }
}  // namespace

__global__ __launch_bounds__(kThreads) void corr_kernel(
    const float* __restrict__ first,
    const float* __restrict__ second,
    float* __restrict__ out)
{
    __shared__ float lds[2 * kBufF];   // 14.6 KB

    const int tid  = threadIdx.x;
    const int p    = tid % kWin;                 // displacement row 0..8
    const int xg   = (tid / kWin) % kXG;         // x-group
    const int ysub = tid / (kWin * kXG);         // 0..1

    // XCD-aware bijective swizzle (512 = 8 x 64)
    int bid = blockIdx.x;
    bid = (bid & 7) * (kBlocks / 8) + (bid >> 3);
    const int b   = bid >> 7;
    const int rem = bid & 127;
    const int y0  = (rem >> 1) * kTY;
    const int wx0 = (rem & 1) * kWH;

    const size_t cstr  = (size_t)kH * kW;
    const size_t ibase = (size_t)b * kC * cstr;

    // --- staging roles: up to 2 float4 per thread per channel ---
    const float* g0 = nullptr; int l0 = -1;
    const float* g1 = nullptr; int l1 = -1;
    {
        int r = tid / kRowC, c = tid - r * kRowC;     // tid < 340: second row
        int y = y0 - kPad + r;
        int gx = wx0 - kPad + 4 * c;
        l0 = (r * kS4 + swz(c)) * 4;
        if (y >= 0 && y < kH && gx >= 0 && gx <= kW - 4)
            g0 = second + ibase + (size_t)y * kW + gx;
    }
    {
        int idx = tid + kThreads;
        if (idx < kNS) {
            int r = idx / kRowC, c = idx - r * kRowC;
            int y = y0 - kPad + r;
            int gx = wx0 - kPad + 4 * c;
            l1 = (r * kS4 + swz(c)) * 4;
            if (y >= 0 && y < kH && gx >= 0 && gx <= kW - 4)
                g1 = second + ibase + (size_t)y * kW + gx;
        } else if (idx < kTot) {
            int i = idx - kNS;
            int ys = i >> 5, c = i & 31;
            l1 = ((kFRow + ys) * kS4 + swz(c)) * 4;
            g1 = first + ibase + (size_t)(y0 + ys) * kW + (wx0 + 4 * c);
        }
    }

    // --- loop-invariant LDS read offsets (floats) ---
    int offw[4], offf[2];
    {
        const int row = ysub + p;
#pragma unroll
        for (int k = 0; k < 4; ++k) offw[k] = (row * kS4 + swz(2 * xg + k)) * 4;
#pragma unroll
        for (int k = 0; k < 2; ++k) offf[k] = ((kFRow + ysub) * kS4 + swz(2 * xg + k)) * 4;
    }

    float acc[kWin * kPX];
#pragma unroll
    for (int i = 0; i < kWin * kPX; ++i) acc[i] = 0.0f;

    auto compute = [&](int cur) {
        const float* buf = &lds[cur * kBufF];
        float w[16], f[8];
        float4 t;
        t = *(const float4*)(buf + offw[0]); w[0]=t.x;  w[1]=t.y;  w[2]=t.z;  w[3]=t.w;
        t = *(const float4*)(buf + offw[1]); w[4]=t.x;  w[5]=t.y;  w[6]=t.z;  w[7]=t.w;
        t = *(const float4*)(buf + offw[2]); w[8]=t.x;  w[9]=t.y;  w[10]=t.z; w[11]=t.w;
        t = *(const float4*)(buf + offw[3]); w[12]=t.x; w[13]=t.y; w[14]=t.z; w[15]=t.w;
        t = *(const float4*)(buf + offf[0]); f[0]=t.x;  f[1]=t.y;  f[2]=t.z;  f[3]=t.w;
        t = *(const float4*)(buf + offf[1]); f[4]=t.x;  f[5]=t.y;  f[6]=t.z;  f[7]=t.w;
#pragma unroll
        for (int o = 0; o < kWin; ++o)
#pragma unroll
            for (int j = 0; j < kPX; ++j)
                acc[o * kPX + j] = fmaf(f[j], w[j + o], acc[o * kPX + j]);
    };

    // --- prologue: stage channel 0 ---
    float4 pf0 = make_float4(0.f, 0.f, 0.f, 0.f);
    float4 pf1 = make_float4(0.f, 0.f, 0.f, 0.f);
    if (g0) { pf0 = *(const float4*)g0; g0 += cstr; }
    if (g1) { pf1 = *(const float4*)g1; g1 += cstr; }
    if (l0 >= 0) *(float4*)&lds[l0] = pf0;
    if (l1 >= 0) *(float4*)&lds[l1] = pf1;
    __syncthreads();

    // --- main loop: prefetch c+1, compute c, write c+1, barrier ---
    int cur = 0;
    for (int c = 0; c < kC - 1; ++c) {
        if (g0) { pf0 = *(const float4*)g0; g0 += cstr; }
        if (g1) { pf1 = *(const float4*)g1; g1 += cstr; }
        compute(cur);
        const int nb = (cur ^ 1) * kBufF;
        if (l0 >= 0) *(float4*)&lds[nb + l0] = pf0;
        if (l1 >= 0) *(float4*)&lds[nb + l1] = pf1;
        __syncthreads();
        cur ^= 1;
    }
    compute(cur);

    // --- epilogue: mean and store ---
    const float inv = 1.0f / (float)kC;
    const size_t obase = (size_t)b * (kWin * kWin) * cstr
                       + (size_t)(y0 + ysub) * kW + wx0 + 8 * xg;
#pragma unroll
    for (int o = 0; o < kWin; ++o) {
        const int d = p * kWin + o;
        float* op = out + obase + (size_t)d * cstr;
        float4 r0, r1;
        r0.x = acc[o * kPX + 0] * inv; r0.y = acc[o * kPX + 1] * inv;
        r0.z = acc[o * kPX + 2] * inv; r0.w = acc[o * kPX + 3] * inv;
        r1.x = acc[o * kPX + 4] * inv; r1.y = acc[o * kPX + 5] * inv;
        r1.z = acc[o * kPX + 6] * inv; r1.w = acc[o * kPX + 7] * inv;
        *(float4*)op = r0;
        *(float4*)(op + 4) = r1;
    }
}

extern "C" void kernel_launch(void* const* d_in, const int* in_sizes, int n_in,
                              void* d_out, int out_size, void* d_ws, size_t ws_size,
                              hipStream_t stream) {
    const float* first  = (const float*)d_in[0];
    const float* second = (const float*)d_in[1];
    float* out = (float*)d_out;
    dim3 grid(kBlocks);      // 512 blocks = 2 per CU
    dim3 block(kThreads);    // 288 threads
    hipLaunchKernelGGL(corr_kernel, grid, block, 0, stream, first, second, out);
}